// Round 1
// baseline (1507.553 us; speedup 1.0000x reference)
//
#include <hip/hip_runtime.h>
#include <stdint.h>

typedef unsigned short u16;
typedef __attribute__((ext_vector_type(8))) short short8;
typedef __attribute__((ext_vector_type(4))) float f32x4;

__device__ __forceinline__ u16 f2bf(float f) {
  uint32_t u = __builtin_bit_cast(uint32_t, f);
  u += 0x7fffu + ((u >> 16) & 1u);
  return (u16)(u >> 16);
}

__device__ __forceinline__ void gld16(const void* g, void* l) {
  __builtin_amdgcn_global_load_lds(
      (const __attribute__((address_space(1))) void*)g,
      (__attribute__((address_space(3))) void*)l, 16, 0, 0);
}

// ---------------------------------------------------------------------------
// Weight prep: build MFMA-fragment-ordered bf16 weights.
// wA: [cb 8][tap 9][kb 8][nl 192][kk 32], nl = g*32+cl, out ch:
//     g<3 : o = g*256 + cb*32+cl, W = w_ih[:, :256] - w_ih[:,256:512]/5
//     g>=3: o = (g-3)*256 + cb*32+cl, W = w_hh
// wS: [cb 8][tap 9][kb 8][nl 96][kk 32], o = cb*96+nl, W = w_ih[:,256:512]/5
// ---------------------------------------------------------------------------
__global__ __launch_bounds__(256) void k_wprep(const float* __restrict__ w_ih,
                                               const float* __restrict__ w_hh,
                                               u16* __restrict__ wA,
                                               u16* __restrict__ wS) {
  const int NA = 8*9*8*192*32;  // 3538944
  const int NS = 8*9*8*96*32;   // 1769472
  for (int idx = blockIdx.x*blockDim.x + threadIdx.x; idx < NA + NS;
       idx += gridDim.x*blockDim.x) {
    if (idx < NA) {
      int kk = idx & 31; int t = idx >> 5;
      int nl = t % 192; t /= 192;
      int kb = t & 7; t >>= 3;
      int tap = t % 9; int cb = t / 9;
      int g = nl >> 5, cl = nl & 31;
      int c = cb*32 + cl, ci = kb*32 + kk;
      float v;
      if (g < 3) {
        int o = g*256 + c;
        v = w_ih[(o*512 + ci)*9 + tap] - 0.2f * w_ih[(o*512 + 256 + ci)*9 + tap];
      } else {
        int o = (g-3)*256 + c;
        v = w_hh[(o*256 + ci)*9 + tap];
      }
      wA[idx] = f2bf(v);
    } else {
      int j = idx - NA;
      int kk = j & 31; int t = j >> 5;
      int nl = t % 96; t /= 96;
      int kb = t & 7; t >>= 3;
      int tap = t % 9; int cb = t / 9;
      int o = cb*96 + nl, ci = kb*32 + kk;
      wS[j] = f2bf(0.2f * w_ih[(o*512 + 256 + ci)*9 + tap]);
    }
  }
}

// ---------------------------------------------------------------------------
// NCHW fp32 master -> NHWC bf16 per-agent x, and per-batch agent-sum s.
// grid (32 pt, 8 ct, 8 b), 256 thr.
// ---------------------------------------------------------------------------
__global__ __launch_bounds__(256) void k_xform(const float* __restrict__ src,
                                               u16* __restrict__ xbf,
                                               u16* __restrict__ sbf) {
  __shared__ float lds[32][33];
  const int t = threadIdx.x;
  const int tx = t & 31, ty = t >> 5;
  const int p0 = blockIdx.x*32, c0 = blockIdx.y*32, b = blockIdx.z;
  const int po = t >> 3, co = (t & 7)*4;
  float ss[4] = {0.f,0.f,0.f,0.f};
  for (int a = 0; a < 6; ++a) {
    const int im = b*6 + a;
    const float* sp = src + ((size_t)im*256 + c0)*1024 + p0;
    #pragma unroll
    for (int k = 0; k < 4; ++k) {
      float v = sp[(size_t)(ty + 8*k)*1024 + tx];
      ss[k] += v;
      lds[ty + 8*k][tx] = v;
    }
    __syncthreads();
    ushort4 pk = make_ushort4(f2bf(lds[co+0][po]), f2bf(lds[co+1][po]),
                              f2bf(lds[co+2][po]), f2bf(lds[co+3][po]));
    *(ushort4*)(xbf + ((size_t)im*1024 + p0+po)*256 + c0 + co) = pk;
    __syncthreads();
  }
  #pragma unroll
  for (int k = 0; k < 4; ++k) lds[ty + 8*k][tx] = ss[k];
  __syncthreads();
  ushort4 pk = make_ushort4(f2bf(lds[co+0][po]), f2bf(lds[co+1][po]),
                            f2bf(lds[co+2][po]), f2bf(lds[co+3][po]));
  *(ushort4*)(sbf + ((size_t)b*1024 + p0+po)*256 + c0 + co) = pk;
}

// ---------------------------------------------------------------------------
// Implicit-GEMM 3x3 conv. W waves, each wave = 1 image row (32 px) x NF*16 n.
// GATES=true: N-perm = 6 gates x 32 ch, fused GRU epilogue -> h_out.
// GATES=false: plain N, writes gsbuf[img][n][pix].
// ---------------------------------------------------------------------------
template<int W, int NF, bool GATES>
__global__ __launch_bounds__(W*64, 2)
void k_conv(const u16* __restrict__ xin, const u16* __restrict__ wpre,
            float* __restrict__ gsbuf,
            const float* __restrict__ b_ih, const float* __restrict__ b_hh,
            const float* __restrict__ h_in, float* __restrict__ h_out) {
  constexpr int NT = W*64;
  constexpr int SLAB = (W+2)*32*32;  // ushorts
  constexpr int BBN  = NF*16*32;
  __shared__ __align__(16) u16 slab[2][SLAB];
  __shared__ __align__(16) u16 bbuf[2][BBN];

  const int tid = threadIdx.x;
  const int l  = tid & 63;
  const int w  = tid >> 6;
  const int lx = l & 15;
  const int lk = l >> 4;

  int bid = blockIdx.x;
  const int cb = bid & 7; bid >>= 3;
  constexpr int MT = 32 / W;
  const int mt = bid % MT;
  const int img = bid / MT;
  const int h0 = mt * W;

  const u16* srcimg = xin + (size_t)img * 1024 * 256;

  auto stageA = [&](int kb, int sb) {
    constexpr int TOT = (W+2)*128;
    #pragma unroll
    for (int ii = 0; ii < (TOT + NT - 1)/NT; ++ii) {
      int i = ii*NT + tid;
      if (i < TOT) {
        int p = i >> 2, ck = i & 3;
        int pr = p >> 5, pc = p & 31;
        int gr = h0 - 1 + pr;
        gr = gr < 0 ? 0 : (gr > 31 ? 31 : gr);
        int sck = ck ^ ((p >> 1) & 3);
        gld16(srcimg + (gr*32 + pc)*256 + kb*32 + sck*8, &slab[sb][i*8]);
      }
    }
  };
  auto stageB = [&](int kb, int tap, int bb) {
    constexpr int TOT = NF*64;
    const u16* wb = wpre + (size_t)((cb*9 + tap)*8 + kb) * (NF*16*32);
    #pragma unroll
    for (int ii = 0; ii < (TOT + NT - 1)/NT; ++ii) {
      int i = ii*NT + tid;
      if (i < TOT) {
        int nl = i >> 2, ck = i & 3;
        int sck = ck ^ ((nl >> 1) & 3);
        gld16(wb + nl*32 + sck*8, &bbuf[bb][i*8]);
      }
    }
  };

  f32x4 acc[2][NF];
  #pragma unroll
  for (int mi = 0; mi < 2; ++mi)
    #pragma unroll
    for (int f = 0; f < NF; ++f) acc[mi][f] = (f32x4){0.f,0.f,0.f,0.f};

  stageA(0, 0);
  stageB(0, 0, 0);
  __syncthreads();

  const int R = h0 + w;
  const int bofs = lx*32 + (lk ^ ((lx >> 1) & 3))*8;

  for (int kb = 0; kb < 8; ++kb) {
    const int sb = kb & 1;
    #pragma unroll
    for (int tap = 0; tap < 9; ++tap) {
      const int bb = (kb*9 + tap) & 1;
      if (tap < 8) {
        stageB(kb, tap+1, bb^1);
      } else if (kb < 7) {
        stageA(kb+1, sb^1);
        stageB(kb+1, 0, bb^1);
      }
      const int dy = tap/3, dx = tap%3;
      const int grow = R + dy - 1;
      const bool rowok = (grow >= 0) && (grow < 32);
      const int sr = w + dy;
      short8 a[2];
      #pragma unroll
      for (int mi = 0; mi < 2; ++mi) {
        int cc = mi*16 + lx + dx - 1;
        bool ok = rowok && (cc >= 0) && (cc < 32);
        int ccc = cc < 0 ? 0 : (cc > 31 ? 31 : cc);
        int pl = sr*32 + ccc;
        short8 av = *(const short8*)&slab[sb][pl*32 + (lk ^ ((ccc >> 1) & 3))*8];
        if (!ok) av = (short8){0,0,0,0,0,0,0,0};
        a[mi] = av;
      }
      const u16* bp = &bbuf[bb][bofs];
      #pragma unroll
      for (int f = 0; f < NF; ++f) {
        short8 bv = *(const short8*)(bp + f*512);
        acc[0][f] = __builtin_amdgcn_mfma_f32_16x16x32_bf16(a[0], bv, acc[0][f], 0, 0, 0);
        acc[1][f] = __builtin_amdgcn_mfma_f32_16x16x32_bf16(a[1], bv, acc[1][f], 0, 0, 0);
      }
      __syncthreads();
    }
  }

  if constexpr (GATES) {
    const int b = img / 6;
    const size_t imgoff = (size_t)img * 256 * 1024;
    #pragma unroll
    for (int q = 0; q < 2; ++q) {
      const int c = cb*32 + q*16 + lx;
      const float bi_r = b_ih[c], bi_i = b_ih[256+c], bi_n = b_ih[512+c];
      const float bh_r = b_hh[c], bh_i = b_hh[256+c], bh_n = b_hh[512+c];
      const float* gs0 = gsbuf + ((size_t)(b*3+0)*256 + c)*1024;
      const float* gs1 = gsbuf + ((size_t)(b*3+1)*256 + c)*1024;
      const float* gs2 = gsbuf + ((size_t)(b*3+2)*256 + c)*1024;
      const float* hip_ = h_in + imgoff + (size_t)c*1024;
      float* hop_ = h_out + imgoff + (size_t)c*1024;
      #pragma unroll
      for (int mi = 0; mi < 2; ++mi) {
        #pragma unroll
        for (int r = 0; r < 4; ++r) {
          const int pix = R*32 + mi*16 + lk*4 + r;
          float ir  = acc[mi][0+q][r]  + gs0[pix] + bi_r;
          float ii  = acc[mi][2+q][r]  + gs1[pix] + bi_i;
          float inn = acc[mi][4+q][r]  + gs2[pix] + bi_n;
          float hr  = acc[mi][6+q][r]  + bh_r;
          float hi2 = acc[mi][8+q][r]  + bh_i;
          float hn  = acc[mi][10+q][r] + bh_n;
          float rg = 1.f/(1.f + __expf(-(ir+hr)));
          float ig = 1.f/(1.f + __expf(-(ii+hi2)));
          float nx = inn + rg*hn;
          nx = nx > 20.f ? 20.f : (nx < -20.f ? -20.f : nx);
          float e2 = __expf(-2.f*nx);
          float ng = (1.f - e2)/(1.f + e2);
          float hold = hip_[pix];
          hop_[pix] = ng + ig*(hold - ng);
        }
      }
    }
  } else {
    #pragma unroll
    for (int f = 0; f < NF; ++f) {
      const int n = cb*(NF*16) + f*16 + lx;
      float* gp = gsbuf + ((size_t)img*768 + n)*1024;
      #pragma unroll
      for (int mi = 0; mi < 2; ++mi)
        #pragma unroll
        for (int r = 0; r < 4; ++r)
          gp[R*32 + mi*16 + lk*4 + r] = acc[mi][f][r];
    }
  }
}

// ---------------------------------------------------------------------------
extern "C" void kernel_launch(void* const* d_in, const int* in_sizes, int n_in,
                              void* d_out, int out_size, void* d_ws, size_t ws_size,
                              hipStream_t stream) {
  const float* x    = (const float*)d_in[0];
  const float* w_ih = (const float*)d_in[1];
  const float* w_hh = (const float*)d_in[2];
  const float* b_ih = (const float*)d_in[3];
  const float* b_hh = (const float*)d_in[4];
  float* out = (float*)d_out;

  char* ws = (char*)d_ws;
  float* m0  = (float*)(ws);                 // 50331648 B master scratch
  u16*  xbf  = (u16*)(ws + 50331648);        // 25165824 B x bf16 NHWC
  u16*  sbf  = (u16*)(ws + 75497472);        //  4194304 B s bf16 NHWC
  float* gsb = (float*)(ws + 79691776);      // 25165824 B gs fp32
  u16*  wA   = (u16*)(ws + 104857600);       //  7077888 B
  u16*  wS   = (u16*)(ws + 111935488);       //  3538944 B  (end 115474432)

  k_wprep<<<2048, 256, 0, stream>>>(w_ih, w_hh, wA, wS);

  for (int it = 0; it < 3; ++it) {
    const float* src = (it == 0) ? x : (it == 1 ? out : m0);
    float* dst = (it == 1) ? m0 : out;
    k_xform<<<dim3(32, 8, 8), 256, 0, stream>>>(src, xbf, sbf);
    k_conv<8, 6, false><<<256, 512, 0, stream>>>(sbf, wS, gsb,
                                                 nullptr, nullptr, nullptr, nullptr);
    k_conv<8, 12, true><<<1536, 512, 0, stream>>>(xbf, wA, gsb,
                                                  b_ih, b_hh, src, dst);
  }
}